// Round 1
// baseline (486.212 us; speedup 1.0000x reference)
//
#include <hip/hip_runtime.h>

// ApplyPolicyMap: fc1 is a fixed one-hot selection matrix [5120, 1858]
// (each column j has exactly one 1.0 at row src_idx[j]).
// => out[b, j] = x_flat[b, src_idx[j]]  — a pure gather, no matmul needed.

#define FLAT   5120
#define NMOVES 1858

// Kernel 1: recover src_idx[j] from fc1 each call (inputs are re-restored
// every launch; no static caching allowed). fc1 is row-major [FLAT, NMOVES]:
// element (i, j) at flat position i*NMOVES + j. Exactly one nonzero per
// column, so plain (non-atomic) writes are race-free and every idx[j] is
// written — no zero-init of d_ws required.
__global__ __launch_bounds__(256) void extract_idx_kernel(
        const float4* __restrict__ fc1_v4, int* __restrict__ idx) {
    const int total4 = (FLAT * NMOVES) / 4;  // 9,512,960 / 4 — exact
    int t = blockIdx.x * blockDim.x + threadIdx.x;
    if (t >= total4) return;
    float4 v = fc1_v4[t];
    int base = t * 4;
    if (v.x != 0.0f) { int e = base;     idx[e % NMOVES] = e / NMOVES; }
    if (v.y != 0.0f) { int e = base + 1; idx[e % NMOVES] = e / NMOVES; }
    if (v.z != 0.0f) { int e = base + 2; idx[e % NMOVES] = e / NMOVES; }
    if (v.w != 0.0f) { int e = base + 3; idx[e % NMOVES] = e / NMOVES; }
}

// Kernel 2: one block per batch row. Stage the full 5120-float row in LDS
// (coalesced float4 loads), then emit coalesced gathered stores.
// LDS = 20 KB -> up to 8 blocks/CU at 160 KB/CU.
__global__ __launch_bounds__(256) void gather_rows_kernel(
        const float* __restrict__ x, const int* __restrict__ idx,
        float* __restrict__ out) {
    __shared__ float row[FLAT];
    const int b = blockIdx.x;

    const float4* xr = (const float4*)(x + (size_t)b * FLAT);
    float4* r4 = (float4*)row;
    // 5120/4 = 1280 float4 loads; 5 per thread at 256 threads.
    #pragma unroll
    for (int i = 0; i < FLAT / 4 / 256; ++i)
        r4[threadIdx.x + i * 256] = xr[threadIdx.x + i * 256];
    __syncthreads();

    float* o = out + (size_t)b * NMOVES;
    // 1858 outputs: 7 full strides of 256 + tail of 66.
    for (int j = threadIdx.x; j < NMOVES; j += 256)
        o[j] = row[idx[j]];
}

extern "C" void kernel_launch(void* const* d_in, const int* in_sizes, int n_in,
                              void* d_out, int out_size, void* d_ws, size_t ws_size,
                              hipStream_t stream) {
    const float* x   = (const float*)d_in[0];   // [16384, 80, 8, 8] fp32
    const float* fc1 = (const float*)d_in[1];   // [5120, 1858] fp32 one-hot
    float* out = (float*)d_out;                 // [16384, 1858] fp32
    int* idx = (int*)d_ws;                      // 1858 ints of scratch

    const int batch = in_sizes[0] / FLAT;       // 16384

    const int total4 = (FLAT * NMOVES) / 4;
    dim3 g1((total4 + 255) / 256), b1(256);
    extract_idx_kernel<<<g1, b1, 0, stream>>>((const float4*)fc1, idx);

    dim3 g2(batch), b2(256);
    gather_rows_kernel<<<g2, b2, 0, stream>>>(x, idx, out);
}